// Round 1
// baseline (84.453 us; speedup 1.0000x reference)
//
#include <hip/hip_runtime.h>

#define IN_C 192
#define HW   9600   // 80*120
#define NPIX_TILE 128

typedef __attribute__((ext_vector_type(8))) short bf16x8;
typedef __attribute__((ext_vector_type(4))) float f32x4;

static __device__ __forceinline__ short f2bf(float f) {
  // round-to-nearest-even fp32 -> bf16 (inputs are finite normals)
  unsigned u = __builtin_bit_cast(unsigned, f);
  u += 0x7FFFu + ((u >> 16) & 1u);
  return (short)(u >> 16);
}

// Pack W (192x192 fp32, row-major [o][k]) into fragment-sequential bf16:
// frag (mo, kk): 64 lanes x 8 bf16 (16B per lane), lane l -> o = mo*16 + (l&15),
// k = kk*32 + (l>>4)*8 + j. Same k(l,j) convention as the x B-frags below, so
// any true intra-fragment k-permutation of the HW layout cancels.
__global__ void pack_w_kernel(const float* __restrict__ W, short* __restrict__ wp) {
  int idx = blockIdx.x * 256 + threadIdx.x;   // 0 .. 12*6*64-1 = 4607
  if (idx >= 12 * 6 * 64) return;
  int mo  = idx / (6 * 64);
  int rem = idx % (6 * 64);
  int kk  = rem / 64;
  int l   = rem % 64;
  int o   = mo * 16 + (l & 15);
  int kb  = kk * 32 + (l >> 4) * 8;
  bf16x8 v;
#pragma unroll
  for (int j = 0; j < 8; ++j) v[j] = f2bf(W[o * IN_C + kb + j]);
  *reinterpret_cast<bf16x8*>(wp + (size_t)idx * 8) = v;
}

// Per-pixel GEMM: D[o][p] = sum_k W[o][k] * x[b][k][p], + bias, then sub-block
// scatter: o -> (co=o>>6, br=(o>>3)&7, bc=o&7); out[b][co][br*80+hi][bc*120+wi].
__global__ __launch_bounds__(256, 2) void conv_mfma_kernel(
    const float* __restrict__ x, const short* __restrict__ wp,
    const float* __restrict__ bias, float* __restrict__ out) {
  const int tid  = threadIdx.x;
  const int wid  = tid >> 6;
  const int lane = tid & 63;
  const int c    = lane & 15;
  const int g    = lane >> 4;
  const int b    = blockIdx.y;
  const int ptile = blockIdx.x * NPIX_TILE;
  const int pw    = ptile + wid * 32;   // this wave's 32-pixel strip

  const float* xb = x + (size_t)b * IN_C * HW;

  f32x4 acc[12][2];
#pragma unroll
  for (int mo = 0; mo < 12; ++mo) {
    acc[mo][0] = (f32x4)0.0f;
    acc[mo][1] = (f32x4)0.0f;
  }

#pragma unroll
  for (int kk = 0; kk < 6; ++kk) {
    // A-frags: W, fragment-sequential, coalesced 16B/lane, L2-resident
    bf16x8 af[12];
#pragma unroll
    for (int mo = 0; mo < 12; ++mo) {
      af[mo] = *reinterpret_cast<const bf16x8*>(
          wp + (size_t)(((mo * 6 + kk) * 64) + lane) * 8);
    }
    // B-frags: x direct from global; lane l -> pixel pw+np*16+c,
    // k = kk*32 + g*8 + j  (8 loads at stride HW, coalesced across lanes)
    bf16x8 bfr[2];
#pragma unroll
    for (int np = 0; np < 2; ++np) {
      const int p = pw + np * 16 + c;
      const float* xp = xb + (size_t)(kk * 32 + g * 8) * HW + p;
      bf16x8 v;
#pragma unroll
      for (int j = 0; j < 8; ++j) v[j] = f2bf(xp[(size_t)j * HW]);
      bfr[np] = v;
    }
#pragma unroll
    for (int mo = 0; mo < 12; ++mo) {
      acc[mo][0] = __builtin_amdgcn_mfma_f32_16x16x32_bf16(af[mo], bfr[0], acc[mo][0], 0, 0, 0);
      acc[mo][1] = __builtin_amdgcn_mfma_f32_16x16x32_bf16(af[mo], bfr[1], acc[mo][1], 0, 0, 0);
    }
  }

  // Epilogue: C/D layout col = lane&15 (pixel), row = (lane>>4)*4 + r (out-ch).
  // Store inst r: 16 consecutive pixels per g-group -> 4 x 64B runs per wave op.
#pragma unroll
  for (int np = 0; np < 2; ++np) {
    const int p  = pw + np * 16 + c;
    const int hi = p / 120;
    const int wi = p - hi * 120;
#pragma unroll
    for (int mo = 0; mo < 12; ++mo) {
      const int ob = mo * 16 + g * 4;
      const f32x4 bv = *reinterpret_cast<const f32x4*>(bias + ob);
      const f32x4 v  = acc[mo][np];
#pragma unroll
      for (int r = 0; r < 4; ++r) {
        const int o  = ob + r;
        const int co = o >> 6;
        const int br = (o >> 3) & 7;
        const int bc = o & 7;
        const int idx = ((b * 3 + co) * 640 + br * 80 + hi) * 960 + bc * 120 + wi;
        out[idx] = v[r] + bv[r];
      }
    }
  }
}

extern "C" void kernel_launch(void* const* d_in, const int* in_sizes, int n_in,
                              void* d_out, int out_size, void* d_ws, size_t ws_size,
                              hipStream_t stream) {
  const float* x    = (const float*)d_in[0];
  const float* W    = (const float*)d_in[1];
  const float* bias = (const float*)d_in[2];
  float* out = (float*)d_out;
  short* wp  = (short*)d_ws;   // 192*192 bf16 = 73728 B packed-fragment W

  pack_w_kernel<<<18, 256, 0, stream>>>(W, wp);
  dim3 grid(75, 16);  // 75 pixel tiles of 128 (9600 exact), 16 batches
  conv_mfma_kernel<<<grid, 256, 0, stream>>>(x, wp, bias, out);
}